// Round 5
// baseline (1787.356 us; speedup 1.0000x reference)
//
#include <hip/hip_runtime.h>
#include <cstdint>
#include <cstddef>

#define N_NODES 30000
#define N_EDGES 480000
#define EP_EDGES (N_EDGES + N_NODES)   // 510000, with self-loops appended
#define DIM 100
#define NH 4
#define NL 6
#define NG 128

// ---------------------------------------------------------------------------
// Workspace layout (bytes). Peak ~88.6 MB (known-good bound: 112.5 MB).
#define OFF_H       0u            // float [30000][100]
#define OFF_AGG2    12000000u     // float [30000][400]
#define OFF_POS     12000000u     // int   [480000]   (overlay, pre-loop)
#define OFF_DEG     13920000u     // int   [30000]    (overlay, pre-loop)
#define OFF_CURS    14040000u     // int   [30000]    (overlay, pre-loop)
#define OFF_POOL    12000000u     // float [128][100] (overlay, post-loop)
#define OFF_CNT     12051200u     // float [128]      (overlay, post-loop)
#define OFF_SCI     60000000u     // float [30000][4]
#define OFF_SCJ     60480000u     // float [30000][4]
#define OFF_ESC     60960000u     // fp16  [6][510000][4]  (CSR order!)
#define OFF_CWIJ    85440000u     // float [6][100][8]  (c = isJ*4 + h)
#define OFF_CWE     85459200u     // float [24][104]    (c = l*4+h, k padded)
#define OFF_WR      85469184u     // float [6][400][100]
#define OFF_INDPTR  86429184u     // int   [30001]
#define OFF_CSRS    86549248u     // int   [510000]
#define OFF_BSUM    88589248u     // int   [32]

static __device__ __forceinline__ unsigned short f2h(float f) {
  return __builtin_bit_cast(unsigned short, (_Float16)f);
}
static __device__ __forceinline__ float h2f(unsigned short u) {
  return (float)__builtin_bit_cast(_Float16, u);
}

// ---------------------------------------------------------------------------
__global__ __launch_bounds__(256) void k_init(const int* __restrict__ x,
                                              const float* __restrict__ emb,
                                              float* __restrict__ h,
                                              int* __restrict__ deg, int* __restrict__ cursor) {
  int tid = blockIdx.x * 256 + threadIdx.x;
  if (tid < N_NODES * DIM) {
    int n = tid / DIM;
    int d = tid - n * DIM;
    h[tid] = emb[x[n] * DIM + d];
  }
  if (tid < N_NODES) { deg[tid] = 0; cursor[tid] = 0; }
}

// fold W,We with a_i/a_j:  cWij[l][k][c] (c=isJ*4+h), cWe[c][104] (c=l*4+h)
__global__ __launch_bounds__(256) void k_fold(const float* __restrict__ W,
                                              const float* __restrict__ We,
                                              const float* __restrict__ a,
                                              float* __restrict__ cWij, float* __restrict__ cWe) {
  int tid = blockIdx.x * 256 + threadIdx.x;
  if (tid < NL * DIM * 8) {
    int l = tid / 800, r = tid % 800;
    int k = r >> 3, c = r & 7;
    int hh = c & 3, isJ = c >> 2;
    const float* wp = W + (size_t)(l * 400 + hh * 100) * 100 + k;
    const float* ap = a + (size_t)(l * 4 + hh) * 200 + isJ * 100;
    float s = 0.f;
    for (int d = 0; d < 100; ++d) s += wp[(size_t)d * 100] * ap[d];
    cWij[l * 800 + k * 8 + c] = s;
  } else if (tid < NL * DIM * 8 + DIM * 24) {
    int m = tid - NL * DIM * 8;
    int k = m / 24, c = m % 24;
    int l = c >> 2, hh = c & 3;
    const float* wp = We + (size_t)(l * 400 + hh * 100) * 100 + k;
    const float* ap = a + (size_t)(l * 4 + hh) * 200 + 100;
    float s = 0.f;
    for (int d = 0; d < 100; ++d) s += wp[(size_t)d * 100] * ap[d];
    cWe[c * 104 + k] = s;
  }
}

// Wr[l][h*100+k][d] = W[l][h*100+d][k]
__global__ __launch_bounds__(256) void k_trW(const float* __restrict__ W, float* __restrict__ Wr) {
  int tid = blockIdx.x * 256 + threadIdx.x;
  if (tid >= NL * 400 * 100) return;
  int d = tid % 100;
  int j2 = tid / 100;
  int k = j2 % 100;
  int hh = (j2 / 100) & 3;
  int l = j2 / 400;
  Wr[tid] = W[(size_t)(l * 400 + hh * 100 + d) * 100 + k];
}

__global__ __launch_bounds__(256) void k_deg(const int* __restrict__ ei, int* __restrict__ deg) {
  int tid = blockIdx.x * 256 + threadIdx.x;
  if (tid >= EP_EDGES) return;
  int dstn = (tid < N_EDGES) ? ei[N_EDGES + tid] : (tid - N_EDGES);
  atomicAdd(&deg[dstn], 1);
}

// two-level scan: per-block inclusive scan (30 blocks x 1024)
__global__ __launch_bounds__(1024) void k_scan1(const int* __restrict__ deg,
                                                int* __restrict__ indptr, int* __restrict__ bsum) {
  __shared__ int s[1024];
  int t = threadIdx.x;
  int i = blockIdx.x * 1024 + t;
  int v = (i < N_NODES) ? deg[i] : 0;
  s[t] = v;
  __syncthreads();
  for (int off = 1; off < 1024; off <<= 1) {
    int tmp = (t >= off) ? s[t - off] : 0;
    __syncthreads();
    s[t] += tmp;
    __syncthreads();
  }
  if (i < N_NODES) indptr[i + 1] = s[t];
  if (t == 1023) bsum[blockIdx.x] = s[1023];
}
// scan 30 block sums -> exclusive offsets (1 wave)
__global__ __launch_bounds__(64) void k_scan2(int* __restrict__ bsum) {
  int t = threadIdx.x;
  int v = (t < 30) ? bsum[t] : 0;
  int inc = v;
  for (int off = 1; off < 64; off <<= 1) {
    int up = __shfl_up(inc, off);
    if (t >= off) inc += up;
  }
  if (t < 30) bsum[t] = inc - v;   // exclusive
}
__global__ __launch_bounds__(1024) void k_scan3(int* __restrict__ indptr,
                                                const int* __restrict__ bsum) {
  int i = blockIdx.x * 1024 + threadIdx.x;
  if (i < N_NODES) indptr[i + 1] += bsum[blockIdx.x];
  if (i == 0) indptr[0] = 0;
}

// build CSR; record pos[eid]=p for real edges; zero esc slots for self-loops
__global__ __launch_bounds__(256) void k_scatter(const int* __restrict__ ei,
                                                 const int* __restrict__ indptr,
                                                 int* __restrict__ cursor,
                                                 int* __restrict__ csr_src,
                                                 int* __restrict__ pos,
                                                 unsigned short* __restrict__ esc) {
  int tid = blockIdx.x * 256 + threadIdx.x;
  if (tid >= EP_EDGES) return;
  int dstn = (tid < N_EDGES) ? ei[N_EDGES + tid] : (tid - N_EDGES);
  int srcn = (tid < N_EDGES) ? ei[tid] : (tid - N_EDGES);
  int p = indptr[dstn] + atomicAdd(&cursor[dstn], 1);
  csr_src[p] = srcn;
  if (tid < N_EDGES) {
    pos[tid] = p;
  } else {
#pragma unroll
    for (int l = 0; l < NL; ++l) {
      ushort4 z; z.x = 0; z.y = 0; z.z = 0; z.w = 0;
      *(ushort4*)(esc + ((size_t)l * EP_EDGES + p) * 4) = z;
    }
  }
}

// esc[l][pos[e]][h] = fp16( edge_attr[e,:] . cWe[l*4+h,:] )
// 384 threads = 6 waves (one layer each) x 64 edge slots; 64 edges/block.
// Weights read via SCALAR loads (wave-uniform lg) -> SMEM pipe, not LDS pipe.
__global__ __launch_bounds__(384) void k_escore(const float* __restrict__ ea,
                                                const float* __restrict__ cWe,
                                                const int* __restrict__ pos,
                                                unsigned short* __restrict__ esc) {
  __shared__ __align__(16) float s_ea[64 * 100];   // 25.6 KB
  int t = threadIdx.x;
  const float4* g4 = (const float4*)(ea + (size_t)blockIdx.x * 6400);
  float4* l4 = (float4*)s_ea;
  for (int i = t; i < 1600; i += 384) l4[i] = g4[i];     // coalesced stage
  __syncthreads();

  int slot = t & 63;
  int lg = __builtin_amdgcn_readfirstlane(t >> 6);   // wave-uniform layer id
  const float* r0 = s_ea + slot * 100;
  const float* wl = cWe + (lg * 4) * 104;            // SGPR base -> s_load
  float acc0[4] = {0.f, 0.f, 0.f, 0.f};
#pragma unroll
  for (int k4 = 0; k4 < 25; ++k4) {
    float4 x0 = *(const float4*)(r0 + k4 * 4);
#pragma unroll
    for (int hh = 0; hh < 4; ++hh) {
      float4 w = *(const float4*)(wl + hh * 104 + k4 * 4);  // scalar pipe
      acc0[hh] = fmaf(x0.w, w.w, fmaf(x0.z, w.z, fmaf(x0.y, w.y, fmaf(x0.x, w.x, acc0[hh]))));
    }
  }
  int e0 = blockIdx.x * 64 + slot;
  int p0 = pos[e0];
  ushort4 o0;
  o0.x = f2h(acc0[0]); o0.y = f2h(acc0[1]); o0.z = f2h(acc0[2]); o0.w = f2h(acc0[3]);
  *(ushort4*)(esc + ((size_t)lg * EP_EDGES + p0) * 4) = o0;
}

// per-node attention scores: sc_i[n,h], sc_j[n,h]
__global__ __launch_bounds__(256) void k_score(const float* __restrict__ h,
                                               const float* __restrict__ cw,  // [100][8]
                                               float* __restrict__ sc_i, float* __restrict__ sc_j) {
  __shared__ __align__(16) float s[DIM * 8];
  for (int i = threadIdx.x; i < DIM * 8; i += 256) s[i] = cw[i];
  __syncthreads();
  int n = blockIdx.x * 256 + threadIdx.x;
  if (n >= N_NODES) return;
  float acc[8] = {0.f, 0.f, 0.f, 0.f, 0.f, 0.f, 0.f, 0.f};
  const float* hr = h + (size_t)n * DIM;
  for (int k4 = 0; k4 < 25; ++k4) {
    float4 v = *(const float4*)(hr + k4 * 4);
    float vv[4] = {v.x, v.y, v.z, v.w};
#pragma unroll
    for (int kk = 0; kk < 4; ++kk) {
      const float* sr = s + (k4 * 4 + kk) * 8;
#pragma unroll
      for (int c = 0; c < 8; ++c) acc[c] += vv[kk] * sr[c];
    }
  }
  *(float4*)(sc_i + (size_t)n * 4) = make_float4(acc[0], acc[1], acc[2], acc[3]);
  *(float4*)(sc_j + (size_t)n * 4) = make_float4(acc[4], acc[5], acc[6], acc[7]);
}

#define ALPHA_P(pp)                                                                  \
  int s_ = csr_src[pp];                                                              \
  float4 sj_ = *(const float4*)(sc_j + (size_t)s_ * 4);                              \
  ushort4 eb_ = *(const ushort4*)(esc_l + (size_t)(pp) * 4);                         \
  float a0 = si.x + sj_.x + h2f(eb_.x); a0 = a0 > 0.f ? a0 : 0.2f * a0;              \
  float a1 = si.y + sj_.y + h2f(eb_.y); a1 = a1 > 0.f ? a1 : 0.2f * a1;              \
  float a2 = si.z + sj_.z + h2f(eb_.z); a2 = a2 > 0.f ? a2 : 0.2f * a2;              \
  float a3 = si.w + sj_.w + h2f(eb_.w); a3 = a3 > 0.f ? a3 : 0.2f * a3;

// one wave per node: segment softmax + weighted gather of h[src].
// Fast path broadcasts (src, w0..w3) via ONE packed LDS b128 broadcast per edge
// (same-address read = conflict-free) instead of 5 ds_bpermute.
__global__ __launch_bounds__(256) void k_aggr(const float* __restrict__ h,
                                              const float* __restrict__ sc_i,
                                              const float* __restrict__ sc_j,
                                              const unsigned short* __restrict__ esc_l,
                                              const int* __restrict__ indptr,
                                              const int* __restrict__ csr_src,
                                              float* __restrict__ agg2) {
  __shared__ __align__(16) uint4 s_pack[4][64];   // 4 KB, per-wave region
  int wave = threadIdx.x >> 6;
  int lane = threadIdx.x & 63;
  int n = blockIdx.x * 4 + wave;                  // 7500*4 == 30000: no early-out
  int start = indptr[n], end = indptr[n + 1];
  int deg = end - start;
  float4 si = *(const float4*)(sc_i + (size_t)n * 4);
  float A0 = 0.f, A1 = 0.f, A2 = 0.f, A3 = 0.f;
  float B0 = 0.f, B1 = 0.f, B2 = 0.f, B3 = 0.f;
  bool has2 = lane < (DIM - 64);

  if (deg <= 64) {
    // ---- fast path: one edge per lane, single alpha computation ----
    int p = start + lane;
    bool act = p < end;
    int srcr = 0;
    float a0 = -1e30f, a1 = -1e30f, a2 = -1e30f, a3 = -1e30f;
    if (act) {
      int s2 = csr_src[p];
      float4 sj2 = *(const float4*)(sc_j + (size_t)s2 * 4);
      ushort4 eb2 = *(const ushort4*)(esc_l + (size_t)p * 4);
      a0 = si.x + sj2.x + h2f(eb2.x); a0 = a0 > 0.f ? a0 : 0.2f * a0;
      a1 = si.y + sj2.y + h2f(eb2.y); a1 = a1 > 0.f ? a1 : 0.2f * a1;
      a2 = si.z + sj2.z + h2f(eb2.z); a2 = a2 > 0.f ? a2 : 0.2f * a2;
      a3 = si.w + sj2.w + h2f(eb2.w); a3 = a3 > 0.f ? a3 : 0.2f * a3;
      srcr = s2;
    }
    float m0 = a0, m1 = a1, m2 = a2, m3 = a3;
    for (int off = 32; off; off >>= 1) {
      m0 = fmaxf(m0, __shfl_xor(m0, off));
      m1 = fmaxf(m1, __shfl_xor(m1, off));
      m2 = fmaxf(m2, __shfl_xor(m2, off));
      m3 = fmaxf(m3, __shfl_xor(m3, off));
    }
    float e0 = act ? __expf(a0 - m0) : 0.f;
    float e1 = act ? __expf(a1 - m1) : 0.f;
    float e2 = act ? __expf(a2 - m2) : 0.f;
    float e3 = act ? __expf(a3 - m3) : 0.f;
    float d0 = e0, d1 = e1, d2 = e2, d3 = e3;
    for (int off = 32; off; off >>= 1) {
      d0 += __shfl_xor(d0, off); d1 += __shfl_xor(d1, off);
      d2 += __shfl_xor(d2, off); d3 += __shfl_xor(d3, off);
    }
    float w0 = e0 * (1.f / (d0 + 1e-16f));
    float w1 = e1 * (1.f / (d1 + 1e-16f));
    float w2 = e2 * (1.f / (d2 + 1e-16f));
    float w3 = e3 * (1.f / (d3 + 1e-16f));
    // pack (src, fp16 w0..w3) -> one 16B broadcast read per edge in j-loop
    uint4 pk;
    pk.x = (unsigned)srcr;
    pk.y = (unsigned)f2h(w0) | ((unsigned)f2h(w1) << 16);
    pk.z = (unsigned)f2h(w2) | ((unsigned)f2h(w3) << 16);
    pk.w = 0u;
    s_pack[wave][lane] = pk;   // wave-synchronous; compiler inserts lgkmcnt
    for (int j = 0; j < deg; ++j) {
      uint4 pk2 = s_pack[wave][j];          // same addr across lanes: broadcast
      int sj2 = (int)pk2.x;
      float q0 = h2f((unsigned short)(pk2.y & 0xffffu));
      float q1 = h2f((unsigned short)(pk2.y >> 16));
      float q2 = h2f((unsigned short)(pk2.z & 0xffffu));
      float q3 = h2f((unsigned short)(pk2.z >> 16));
      const float* hr = h + (size_t)sj2 * DIM;
      float hv0 = hr[lane];
      float hv1 = has2 ? hr[64 + lane] : 0.f;
      A0 += q0 * hv0; A1 += q1 * hv0; A2 += q2 * hv0; A3 += q3 * hv0;
      B0 += q0 * hv1; B1 += q1 * hv1; B2 += q2 * hv1; B3 += q3 * hv1;
    }
  } else {
    // ---- generic path (deg > 64): 3-pass recompute (rare) ----
    float m0 = -1e30f, m1 = -1e30f, m2 = -1e30f, m3 = -1e30f;
    for (int p = start + lane; p < end; p += 64) {
      ALPHA_P(p)
      (void)s_;
      m0 = fmaxf(m0, a0); m1 = fmaxf(m1, a1); m2 = fmaxf(m2, a2); m3 = fmaxf(m3, a3);
    }
    for (int off = 32; off; off >>= 1) {
      m0 = fmaxf(m0, __shfl_xor(m0, off));
      m1 = fmaxf(m1, __shfl_xor(m1, off));
      m2 = fmaxf(m2, __shfl_xor(m2, off));
      m3 = fmaxf(m3, __shfl_xor(m3, off));
    }
    float d0 = 0.f, d1 = 0.f, d2 = 0.f, d3 = 0.f;
    for (int p = start + lane; p < end; p += 64) {
      ALPHA_P(p)
      (void)s_;
      d0 += __expf(a0 - m0); d1 += __expf(a1 - m1);
      d2 += __expf(a2 - m2); d3 += __expf(a3 - m3);
    }
    for (int off = 32; off; off >>= 1) {
      d0 += __shfl_xor(d0, off); d1 += __shfl_xor(d1, off);
      d2 += __shfl_xor(d2, off); d3 += __shfl_xor(d3, off);
    }
    float i0 = 1.f / (d0 + 1e-16f), i1 = 1.f / (d1 + 1e-16f);
    float i2 = 1.f / (d2 + 1e-16f), i3 = 1.f / (d3 + 1e-16f);
    for (int base = start; base < end; base += 64) {
      int cntv = min(64, end - base);
      int p = base + lane;
      float w0 = 0.f, w1 = 0.f, w2 = 0.f, w3 = 0.f;
      int srcr = 0;
      if (p < end) {
        ALPHA_P(p)
        w0 = __expf(a0 - m0) * i0; w1 = __expf(a1 - m1) * i1;
        w2 = __expf(a2 - m2) * i2; w3 = __expf(a3 - m3) * i3;
        srcr = s_;
      }
      for (int j = 0; j < cntv; ++j) {
        int sj2 = __shfl(srcr, j);
        float q0 = __shfl(w0, j), q1 = __shfl(w1, j);
        float q2 = __shfl(w2, j), q3 = __shfl(w3, j);
        const float* hr = h + (size_t)sj2 * DIM;
        float hv0 = hr[lane];
        float hv1 = has2 ? hr[64 + lane] : 0.f;
        A0 += q0 * hv0; A1 += q1 * hv0; A2 += q2 * hv0; A3 += q3 * hv0;
        B0 += q0 * hv1; B1 += q1 * hv1; B2 += q2 * hv1; B3 += q3 * hv1;
      }
    }
  }
  float* outp = agg2 + (size_t)n * 400;
  outp[lane] = A0; outp[100 + lane] = A1; outp[200 + lane] = A2; outp[300 + lane] = A3;
  if (has2) {
    outp[64 + lane] = B0; outp[164 + lane] = B1; outp[264 + lane] = B2; outp[364 + lane] = B3;
  }
}

// GEMM2: out = agg2[N,400] @ Wr_l[400,100], fused LayerNorm + ELU + residual.
// Lane = output col d (lane, 64+lane); wave = 8 node-rows; A rows are
// wave-uniform -> scalar loads (SMEM pipe); B transposed in LDS Bt[d][k]
// (pad 108: 16B-aligned b128, lane-stride 12 banks -> conflict-free).
#define G2_BPAD 108
__global__ __launch_bounds__(256) void k_gemm2(const float* __restrict__ agg2,
                                               const float* __restrict__ Wr_l,
                                               const float* __restrict__ lg,
                                               const float* __restrict__ lb,
                                               float* __restrict__ h) {
  __shared__ __align__(16) float Bt[100][G2_BPAD];   // 43.2 KB
  int t = threadIdx.x;
  int lane = t & 63;
  int w = __builtin_amdgcn_readfirstlane(t >> 6);    // wave-uniform
  int nbase = blockIdx.x * 32 + w * 8;               // 8 rows per wave
  const float* A0p = agg2 + (size_t)nbase * 400;     // uniform -> s_load

  float acc0[8], acc1[8];
#pragma unroll
  for (int i = 0; i < 8; ++i) { acc0[i] = 0.f; acc1[i] = 0.f; }
  bool has2 = lane < (DIM - 64);
  int lane2 = 64 + lane;

  for (int kt = 0; kt < 4; ++kt) {
    __syncthreads();
    // stage transposed chunk: Bt[d][k] = Wr_l[(kt*100+k)*100 + d]
    for (int idx = t; idx < 10000; idx += 256) {
      int k = idx / 100, d = idx - k * 100;     // consecutive t -> d+1: coalesced
      Bt[d][k] = Wr_l[(size_t)(kt * 100 + k) * 100 + d];
    }
    __syncthreads();
    const float* Ak = A0p + kt * 100;
    for (int k4 = 0; k4 < 25; ++k4) {
      float4 b0 = *(const float4*)&Bt[lane][k4 * 4];
      float4 b1 = make_float4(0.f, 0.f, 0.f, 0.f);
      if (has2) b1 = *(const float4*)&Bt[lane2][k4 * 4];
#pragma unroll
      for (int i = 0; i < 8; ++i) {
        float4 a = *(const float4*)(Ak + (size_t)i * 400 + k4 * 4);  // s_load x4
        acc0[i] = fmaf(a.w, b0.w, fmaf(a.z, b0.z, fmaf(a.y, b0.y, fmaf(a.x, b0.x, acc0[i]))));
        acc1[i] = fmaf(a.w, b1.w, fmaf(a.z, b1.z, fmaf(a.y, b1.y, fmaf(a.x, b1.x, acc1[i]))));
      }
    }
  }

  // epilogue: LN over d (across lanes), ELU, residual
  float glo = lg[lane], blo = lb[lane];
  float ghi = has2 ? lg[lane2] : 0.f;
  float bhi = has2 ? lb[lane2] : 0.f;
#pragma unroll
  for (int i = 0; i < 8; ++i) {
    int n = nbase + i;
    float v0 = acc0[i];
    float v1 = has2 ? acc1[i] : 0.f;
    float s = v0 + v1;
    for (int off = 32; off; off >>= 1) s += __shfl_xor(s, off);
    float mu = s * 0.01f;
    float d0 = v0 - mu;
    float d1 = has2 ? (v1 - mu) : 0.f;
    float s2 = d0 * d0 + d1 * d1;
    for (int off = 32; off; off >>= 1) s2 += __shfl_xor(s2, off);
    float rstd = rsqrtf(s2 * 0.01f + 1e-5f);
    if (n < N_NODES) {
      float* hp = h + (size_t)n * DIM;
      float y0 = d0 * rstd * glo + blo;
      y0 = y0 > 0.f ? y0 : (__expf(y0) - 1.f);
      hp[lane] += y0;
      if (has2) {
        float y1 = d1 * rstd * ghi + bhi;
        y1 = y1 > 0.f ? y1 : (__expf(y1) - 1.f);
        hp[lane2] += y1;
      }
    }
  }
}

// pool via run-length accumulation (batch is sorted): ~2 atomics/dim/block
__global__ __launch_bounds__(128) void k_pool(const float* __restrict__ h,
                                              const int* __restrict__ batch,
                                              float* __restrict__ pooled, float* __restrict__ cnt) {
  int d = threadIdx.x;
  int n0 = blockIdx.x * 64;
  int n1 = min(n0 + 64, N_NODES);
  if (n0 >= N_NODES) return;
  int curg = -1;
  float acc = 0.f, c = 0.f;
  for (int n = n0; n < n1; ++n) {
    int g = batch[n];
    if (g != curg) {
      if (curg >= 0) {
        if (d < 100) atomicAdd(&pooled[(size_t)curg * DIM + d], acc);
        if (d == 0) atomicAdd(&cnt[curg], c);
      }
      curg = g; acc = 0.f; c = 0.f;
    }
    if (d < 100) acc += h[(size_t)n * DIM + d];
    c += 1.f;
  }
  if (curg >= 0) {
    if (d < 100) atomicAdd(&pooled[(size_t)curg * DIM + d], acc);
    if (d == 0) atomicAdd(&cnt[curg], c);
  }
}

__global__ __launch_bounds__(64) void k_mlp(const float* __restrict__ pooled,
                                            const float* __restrict__ cnt,
                                            const float* __restrict__ w1, const float* __restrict__ b1,
                                            const float* __restrict__ w2, const float* __restrict__ b2,
                                            float* __restrict__ out) {
  int g = blockIdx.x;
  int j = threadIdx.x;
  float invc = 1.0f / fmaxf(cnt[g], 1.0f);
  const float* pr = pooled + (size_t)g * DIM;
  const float* wr = w1 + (size_t)j * DIM;
  float acc = 0.f;
  for (int k = 0; k < DIM; ++k) acc += pr[k] * wr[k];
  float hh = acc * invc + b1[j];
  out[NG + g * 64 + j] = hh;
  float v = hh * w2[j];
  for (int off = 32; off; off >>= 1) v += __shfl_xor(v, off);
  if (j == 0) out[g] = v + b2[0];
}

// ---------------------------------------------------------------------------
extern "C" void kernel_launch(void* const* d_in, const int* in_sizes, int n_in,
                              void* d_out, int out_size, void* d_ws, size_t ws_size,
                              hipStream_t stream) {
  (void)in_sizes; (void)n_in; (void)out_size; (void)ws_size;
  const int* x = (const int*)d_in[0];
  const int* ei = (const int*)d_in[1];
  const float* ea = (const float*)d_in[2];
  const int* batch = (const int*)d_in[3];
  const float* emb = (const float*)d_in[4];
  const float* W = (const float*)d_in[5];
  const float* We = (const float*)d_in[6];
  const float* a = (const float*)d_in[7];
  const float* ln_g = (const float*)d_in[8];
  const float* ln_b = (const float*)d_in[9];
  const float* w1 = (const float*)d_in[10];
  const float* b1 = (const float*)d_in[11];
  const float* w2 = (const float*)d_in[12];
  const float* b2 = (const float*)d_in[13];
  float* outp = (float*)d_out;

  char* ws = (char*)d_ws;
  float* h = (float*)(ws + OFF_H);
  float* agg2 = (float*)(ws + OFF_AGG2);
  int* pos = (int*)(ws + OFF_POS);
  int* deg = (int*)(ws + OFF_DEG);
  int* cursor = (int*)(ws + OFF_CURS);
  float* pooled = (float*)(ws + OFF_POOL);
  float* cnt = (float*)(ws + OFF_CNT);
  float* sc_i = (float*)(ws + OFF_SCI);
  float* sc_j = (float*)(ws + OFF_SCJ);
  unsigned short* esc = (unsigned short*)(ws + OFF_ESC);
  float* cWij = (float*)(ws + OFF_CWIJ);
  float* cWe = (float*)(ws + OFF_CWE);
  float* Wr = (float*)(ws + OFF_WR);
  int* indptr = (int*)(ws + OFF_INDPTR);
  int* csr_src = (int*)(ws + OFF_CSRS);
  int* bsum = (int*)(ws + OFF_BSUM);

  k_init<<<11719, 256, 0, stream>>>(x, emb, h, deg, cursor);
  k_fold<<<29, 256, 0, stream>>>(W, We, a, cWij, cWe);
  k_trW<<<938, 256, 0, stream>>>(W, Wr);
  k_deg<<<1993, 256, 0, stream>>>(ei, deg);
  k_scan1<<<30, 1024, 0, stream>>>(deg, indptr, bsum);
  k_scan2<<<1, 64, 0, stream>>>(bsum);
  k_scan3<<<30, 1024, 0, stream>>>(indptr, bsum);
  k_scatter<<<1993, 256, 0, stream>>>(ei, indptr, cursor, csr_src, pos, esc);
  k_escore<<<7500, 384, 0, stream>>>(ea, cWe, pos, esc);

  for (int l = 0; l < NL; ++l) {
    k_score<<<118, 256, 0, stream>>>(h, cWij + l * 800, sc_i, sc_j);
    k_aggr<<<7500, 256, 0, stream>>>(h, sc_i, sc_j, esc + (size_t)l * EP_EDGES * 4,
                                     indptr, csr_src, agg2);
    k_gemm2<<<938, 256, 0, stream>>>(agg2, Wr + (size_t)l * 40000,
                                     ln_g + l * 100, ln_b + l * 100, h);
  }

  hipMemsetAsync(ws + OFF_POOL, 0, 51200 + 512, stream);
  k_pool<<<469, 128, 0, stream>>>(h, batch, pooled, cnt);
  k_mlp<<<128, 64, 0, stream>>>(pooled, cnt, w1, b1, w2, b2, outp);
}

// Round 6
// 830.889 us; speedup vs baseline: 2.1511x; 2.1511x over previous
//
#include <hip/hip_runtime.h>
#include <cstdint>
#include <cstddef>

#define N_NODES 30000
#define N_EDGES 480000
#define EP_EDGES (N_EDGES + N_NODES)   // 510000, with self-loops appended
#define DIM 100
#define NH 4
#define NL 6
#define NG 128
#define KP 416                         // GEMM2 K padded to 13*32

// ---------------------------------------------------------------------------
// Workspace layout (bytes). Peak ~88 MB (known-good bound: 112.5 MB).
#define OFF_H       0u            // float [30000][100]
#define OFF_AGG2    12000000u     // fp16  [30000][416]  (24.96 MB)
#define OFF_POS     12000000u     // int   [480000]   (overlay, pre-loop)
#define OFF_DEG     13920000u     // int   [30000]    (overlay, pre-loop)
#define OFF_CURS    14040000u     // int   [30000]    (overlay, pre-loop)
#define OFF_POOL    12000000u     // float [128][100] (overlay, post-loop)
#define OFF_CNT     12051200u     // float [128]      (overlay, post-loop)
#define OFF_SCI     60000000u     // float [30000][4]
#define OFF_SCJ     60480000u     // float [30000][4]
#define OFF_ESC     60960000u     // fp16  [6][510000][4]  (CSR order!)
#define OFF_CWIJ    85440000u     // float [6][100][8]  (c = isJ*4 + h)
#define OFF_CWE     85459200u     // float [24][104]    (c = l*4+h, k padded)
#define OFF_WR      85469184u     // fp16  Bfrag [6][7][13][64][8]  (559 KB)
#define OFF_INDPTR  86429184u     // int   [30001]
#define OFF_CSRS    86549248u     // int   [510000]
#define OFF_BSUM    88589248u     // int   [32]

typedef _Float16 half8 __attribute__((ext_vector_type(8)));
typedef float f32x4 __attribute__((ext_vector_type(4)));

static __device__ __forceinline__ unsigned short f2h(float f) {
  return __builtin_bit_cast(unsigned short, (_Float16)f);
}
static __device__ __forceinline__ float h2f(unsigned short u) {
  return (float)__builtin_bit_cast(_Float16, u);
}

// ---------------------------------------------------------------------------
__global__ __launch_bounds__(256) void k_init(const int* __restrict__ x,
                                              const float* __restrict__ emb,
                                              float* __restrict__ h,
                                              int* __restrict__ deg, int* __restrict__ cursor) {
  int tid = blockIdx.x * 256 + threadIdx.x;
  if (tid < N_NODES * DIM) {
    int n = tid / DIM;
    int d = tid - n * DIM;
    h[tid] = emb[x[n] * DIM + d];
  }
  if (tid < N_NODES) { deg[tid] = 0; cursor[tid] = 0; }
}

// fold W,We with a_i/a_j:  cWij[l][k][c] (c=isJ*4+h), cWe[c][104] (c=l*4+h)
__global__ __launch_bounds__(256) void k_fold(const float* __restrict__ W,
                                              const float* __restrict__ We,
                                              const float* __restrict__ a,
                                              float* __restrict__ cWij, float* __restrict__ cWe) {
  int tid = blockIdx.x * 256 + threadIdx.x;
  if (tid < NL * DIM * 8) {
    int l = tid / 800, r = tid % 800;
    int k = r >> 3, c = r & 7;
    int hh = c & 3, isJ = c >> 2;
    const float* wp = W + (size_t)(l * 400 + hh * 100) * 100 + k;
    const float* ap = a + (size_t)(l * 4 + hh) * 200 + isJ * 100;
    float s = 0.f;
    for (int d = 0; d < 100; ++d) s += wp[(size_t)d * 100] * ap[d];
    cWij[l * 800 + k * 8 + c] = s;
  } else if (tid < NL * DIM * 8 + DIM * 24) {
    int m = tid - NL * DIM * 8;
    int k = m / 24, c = m % 24;
    int l = c >> 2, hh = c & 3;
    const float* wp = We + (size_t)(l * 400 + hh * 100) * 100 + k;
    const float* ap = a + (size_t)(l * 4 + hh) * 200 + 100;
    float s = 0.f;
    for (int d = 0; d < 100; ++d) s += wp[(size_t)d * 100] * ap[d];
    cWe[c * 104 + k] = s;
  }
}

// Bfrag[l][ct][ks][lane][j] (f16) = B[k][n] in MFMA B-operand order:
//   k = ks*32 + (lane>>4)*8 + j,  n = ct*16 + (lane&15)
//   B[k=hh*100+kk][n] = W[l][hh*100 + n][kk]   (zeros in pads)
__global__ __launch_bounds__(256) void k_bfrag(const float* __restrict__ W,
                                               unsigned short* __restrict__ Bfrag) {
  int tid = blockIdx.x * 256 + threadIdx.x;
  if (tid >= NL * 7 * 13 * 64 * 8) return;
  int j = tid & 7;
  int lane = (tid >> 3) & 63;
  int rest = tid >> 9;          // ((l*7+ct)*13+ks)
  int ks = rest % 13;
  int rest2 = rest / 13;
  int ct = rest2 % 7;
  int l = rest2 / 7;
  int k = ks * 32 + ((lane >> 4) << 3) + j;
  int n = ct * 16 + (lane & 15);
  float v = 0.f;
  if (k < 400 && n < 100) {
    int hh = k / 100, kk = k - hh * 100;
    v = W[(size_t)(l * 400 + hh * 100 + n) * 100 + kk];
  }
  Bfrag[tid] = f2h(v);
}

__global__ __launch_bounds__(256) void k_deg(const int* __restrict__ ei, int* __restrict__ deg) {
  int tid = blockIdx.x * 256 + threadIdx.x;
  if (tid >= EP_EDGES) return;
  int dstn = (tid < N_EDGES) ? ei[N_EDGES + tid] : (tid - N_EDGES);
  atomicAdd(&deg[dstn], 1);
}

// two-level scan: per-block inclusive scan (30 blocks x 1024)
__global__ __launch_bounds__(1024) void k_scan1(const int* __restrict__ deg,
                                                int* __restrict__ indptr, int* __restrict__ bsum) {
  __shared__ int s[1024];
  int t = threadIdx.x;
  int i = blockIdx.x * 1024 + t;
  int v = (i < N_NODES) ? deg[i] : 0;
  s[t] = v;
  __syncthreads();
  for (int off = 1; off < 1024; off <<= 1) {
    int tmp = (t >= off) ? s[t - off] : 0;
    __syncthreads();
    s[t] += tmp;
    __syncthreads();
  }
  if (i < N_NODES) indptr[i + 1] = s[t];
  if (t == 1023) bsum[blockIdx.x] = s[1023];
}
// scan 30 block sums -> exclusive offsets (1 wave)
__global__ __launch_bounds__(64) void k_scan2(int* __restrict__ bsum) {
  int t = threadIdx.x;
  int v = (t < 30) ? bsum[t] : 0;
  int inc = v;
  for (int off = 1; off < 64; off <<= 1) {
    int up = __shfl_up(inc, off);
    if (t >= off) inc += up;
  }
  if (t < 30) bsum[t] = inc - v;   // exclusive
}
__global__ __launch_bounds__(1024) void k_scan3(int* __restrict__ indptr,
                                                const int* __restrict__ bsum) {
  int i = blockIdx.x * 1024 + threadIdx.x;
  if (i < N_NODES) indptr[i + 1] += bsum[blockIdx.x];
  if (i == 0) indptr[0] = 0;
}

// build CSR; record pos[eid]=p for real edges; zero esc slots for self-loops
__global__ __launch_bounds__(256) void k_scatter(const int* __restrict__ ei,
                                                 const int* __restrict__ indptr,
                                                 int* __restrict__ cursor,
                                                 int* __restrict__ csr_src,
                                                 int* __restrict__ pos,
                                                 unsigned short* __restrict__ esc) {
  int tid = blockIdx.x * 256 + threadIdx.x;
  if (tid >= EP_EDGES) return;
  int dstn = (tid < N_EDGES) ? ei[N_EDGES + tid] : (tid - N_EDGES);
  int srcn = (tid < N_EDGES) ? ei[tid] : (tid - N_EDGES);
  int p = indptr[dstn] + atomicAdd(&cursor[dstn], 1);
  csr_src[p] = srcn;
  if (tid < N_EDGES) {
    pos[tid] = p;
  } else {
#pragma unroll
    for (int l = 0; l < NL; ++l) {
      ushort4 z; z.x = 0; z.y = 0; z.z = 0; z.w = 0;
      *(ushort4*)(esc + ((size_t)l * EP_EDGES + p) * 4) = z;
    }
  }
}

// esc[l][pos[e]][h] = fp16( edge_attr[e,:] . cWe[l*4+h,:] )
// 384 threads = 6 waves (one layer each) x 64 edge slots; 64 edges/block.
// Weights read via SCALAR loads (wave-uniform lg) -> SMEM pipe, not LDS pipe.
__global__ __launch_bounds__(384) void k_escore(const float* __restrict__ ea,
                                                const float* __restrict__ cWe,
                                                const int* __restrict__ pos,
                                                unsigned short* __restrict__ esc) {
  __shared__ __align__(16) float s_ea[64 * 100];   // 25.6 KB
  int t = threadIdx.x;
  const float4* g4 = (const float4*)(ea + (size_t)blockIdx.x * 6400);
  float4* l4 = (float4*)s_ea;
  for (int i = t; i < 1600; i += 384) l4[i] = g4[i];     // coalesced stage
  __syncthreads();

  int slot = t & 63;
  int lg = __builtin_amdgcn_readfirstlane(t >> 6);   // wave-uniform layer id
  const float* r0 = s_ea + slot * 100;
  const float* wl = cWe + (lg * 4) * 104;            // SGPR base -> s_load
  float acc0[4] = {0.f, 0.f, 0.f, 0.f};
#pragma unroll
  for (int k4 = 0; k4 < 25; ++k4) {
    float4 x0 = *(const float4*)(r0 + k4 * 4);
#pragma unroll
    for (int hh = 0; hh < 4; ++hh) {
      float4 w = *(const float4*)(wl + hh * 104 + k4 * 4);  // scalar pipe
      acc0[hh] = fmaf(x0.w, w.w, fmaf(x0.z, w.z, fmaf(x0.y, w.y, fmaf(x0.x, w.x, acc0[hh]))));
    }
  }
  int e0 = blockIdx.x * 64 + slot;
  int p0 = pos[e0];
  ushort4 o0;
  o0.x = f2h(acc0[0]); o0.y = f2h(acc0[1]); o0.z = f2h(acc0[2]); o0.w = f2h(acc0[3]);
  *(ushort4*)(esc + ((size_t)lg * EP_EDGES + p0) * 4) = o0;
}

// per-node attention scores: sc_i[n,h], sc_j[n,h]
__global__ __launch_bounds__(256) void k_score(const float* __restrict__ h,
                                               const float* __restrict__ cw,  // [100][8]
                                               float* __restrict__ sc_i, float* __restrict__ sc_j) {
  __shared__ __align__(16) float s[DIM * 8];
  for (int i = threadIdx.x; i < DIM * 8; i += 256) s[i] = cw[i];
  __syncthreads();
  int n = blockIdx.x * 256 + threadIdx.x;
  if (n >= N_NODES) return;
  float acc[8] = {0.f, 0.f, 0.f, 0.f, 0.f, 0.f, 0.f, 0.f};
  const float* hr = h + (size_t)n * DIM;
  for (int k4 = 0; k4 < 25; ++k4) {
    float4 v = *(const float4*)(hr + k4 * 4);
    float vv[4] = {v.x, v.y, v.z, v.w};
#pragma unroll
    for (int kk = 0; kk < 4; ++kk) {
      const float* sr = s + (k4 * 4 + kk) * 8;
#pragma unroll
      for (int c = 0; c < 8; ++c) acc[c] += vv[kk] * sr[c];
    }
  }
  *(float4*)(sc_i + (size_t)n * 4) = make_float4(acc[0], acc[1], acc[2], acc[3]);
  *(float4*)(sc_j + (size_t)n * 4) = make_float4(acc[4], acc[5], acc[6], acc[7]);
}

#define ALPHA_P(pp)                                                                  \
  int s_ = csr_src[pp];                                                              \
  float4 sj_ = *(const float4*)(sc_j + (size_t)s_ * 4);                              \
  ushort4 eb_ = *(const ushort4*)(esc_l + (size_t)(pp) * 4);                         \
  float a0 = si.x + sj_.x + h2f(eb_.x); a0 = a0 > 0.f ? a0 : 0.2f * a0;              \
  float a1 = si.y + sj_.y + h2f(eb_.y); a1 = a1 > 0.f ? a1 : 0.2f * a1;              \
  float a2 = si.z + sj_.z + h2f(eb_.z); a2 = a2 > 0.f ? a2 : 0.2f * a2;              \
  float a3 = si.w + sj_.w + h2f(eb_.w); a3 = a3 > 0.f ? a3 : 0.2f * a3;

// one wave per node: segment softmax + weighted gather of h[src].
// Output agg2 is fp16 [n][KP] (K padded with zeros for the MFMA GEMM).
__global__ __launch_bounds__(256) void k_aggr(const float* __restrict__ h,
                                              const float* __restrict__ sc_i,
                                              const float* __restrict__ sc_j,
                                              const unsigned short* __restrict__ esc_l,
                                              const int* __restrict__ indptr,
                                              const int* __restrict__ csr_src,
                                              unsigned short* __restrict__ agg2h) {
  __shared__ __align__(16) uint4 s_pack[4][64];   // 4 KB, per-wave region
  int wave = threadIdx.x >> 6;
  int lane = threadIdx.x & 63;
  int n = blockIdx.x * 4 + wave;                  // 7500*4 == 30000: no early-out
  int start = indptr[n], end = indptr[n + 1];
  int deg = end - start;
  float4 si = *(const float4*)(sc_i + (size_t)n * 4);
  float A0 = 0.f, A1 = 0.f, A2 = 0.f, A3 = 0.f;
  float B0 = 0.f, B1 = 0.f, B2 = 0.f, B3 = 0.f;
  bool has2 = lane < (DIM - 64);

  if (deg <= 64) {
    // ---- fast path: one edge per lane, single alpha computation ----
    int p = start + lane;
    bool act = p < end;
    int srcr = 0;
    float a0 = -1e30f, a1 = -1e30f, a2 = -1e30f, a3 = -1e30f;
    if (act) {
      int s2 = csr_src[p];
      float4 sj2 = *(const float4*)(sc_j + (size_t)s2 * 4);
      ushort4 eb2 = *(const ushort4*)(esc_l + (size_t)p * 4);
      a0 = si.x + sj2.x + h2f(eb2.x); a0 = a0 > 0.f ? a0 : 0.2f * a0;
      a1 = si.y + sj2.y + h2f(eb2.y); a1 = a1 > 0.f ? a1 : 0.2f * a1;
      a2 = si.z + sj2.z + h2f(eb2.z); a2 = a2 > 0.f ? a2 : 0.2f * a2;
      a3 = si.w + sj2.w + h2f(eb2.w); a3 = a3 > 0.f ? a3 : 0.2f * a3;
      srcr = s2;
    }
    float m0 = a0, m1 = a1, m2 = a2, m3 = a3;
    for (int off = 32; off; off >>= 1) {
      m0 = fmaxf(m0, __shfl_xor(m0, off));
      m1 = fmaxf(m1, __shfl_xor(m1, off));
      m2 = fmaxf(m2, __shfl_xor(m2, off));
      m3 = fmaxf(m3, __shfl_xor(m3, off));
    }
    float e0 = act ? __expf(a0 - m0) : 0.f;
    float e1 = act ? __expf(a1 - m1) : 0.f;
    float e2 = act ? __expf(a2 - m2) : 0.f;
    float e3 = act ? __expf(a3 - m3) : 0.f;
    float d0 = e0, d1 = e1, d2 = e2, d3 = e3;
    for (int off = 32; off; off >>= 1) {
      d0 += __shfl_xor(d0, off); d1 += __shfl_xor(d1, off);
      d2 += __shfl_xor(d2, off); d3 += __shfl_xor(d3, off);
    }
    float w0 = e0 * (1.f / (d0 + 1e-16f));
    float w1 = e1 * (1.f / (d1 + 1e-16f));
    float w2 = e2 * (1.f / (d2 + 1e-16f));
    float w3 = e3 * (1.f / (d3 + 1e-16f));
    // pack (src, fp16 w0..w3) -> one 16B broadcast read per edge in j-loop
    uint4 pk;
    pk.x = (unsigned)srcr;
    pk.y = (unsigned)f2h(w0) | ((unsigned)f2h(w1) << 16);
    pk.z = (unsigned)f2h(w2) | ((unsigned)f2h(w3) << 16);
    pk.w = 0u;
    s_pack[wave][lane] = pk;   // wave-synchronous; compiler inserts lgkmcnt
    for (int j = 0; j < deg; ++j) {
      uint4 pk2 = s_pack[wave][j];          // same addr across lanes: broadcast
      int sj2 = (int)pk2.x;
      float q0 = h2f((unsigned short)(pk2.y & 0xffffu));
      float q1 = h2f((unsigned short)(pk2.y >> 16));
      float q2 = h2f((unsigned short)(pk2.z & 0xffffu));
      float q3 = h2f((unsigned short)(pk2.z >> 16));
      const float* hr = h + (size_t)sj2 * DIM;
      float hv0 = hr[lane];
      float hv1 = has2 ? hr[64 + lane] : 0.f;
      A0 += q0 * hv0; A1 += q1 * hv0; A2 += q2 * hv0; A3 += q3 * hv0;
      B0 += q0 * hv1; B1 += q1 * hv1; B2 += q2 * hv1; B3 += q3 * hv1;
    }
  } else {
    // ---- generic path (deg > 64): 3-pass recompute (rare) ----
    float m0 = -1e30f, m1 = -1e30f, m2 = -1e30f, m3 = -1e30f;
    for (int p = start + lane; p < end; p += 64) {
      ALPHA_P(p)
      (void)s_;
      m0 = fmaxf(m0, a0); m1 = fmaxf(m1, a1); m2 = fmaxf(m2, a2); m3 = fmaxf(m3, a3);
    }
    for (int off = 32; off; off >>= 1) {
      m0 = fmaxf(m0, __shfl_xor(m0, off));
      m1 = fmaxf(m1, __shfl_xor(m1, off));
      m2 = fmaxf(m2, __shfl_xor(m2, off));
      m3 = fmaxf(m3, __shfl_xor(m3, off));
    }
    float d0 = 0.f, d1 = 0.f, d2 = 0.f, d3 = 0.f;
    for (int p = start + lane; p < end; p += 64) {
      ALPHA_P(p)
      (void)s_;
      d0 += __expf(a0 - m0); d1 += __expf(a1 - m1);
      d2 += __expf(a2 - m2); d3 += __expf(a3 - m3);
    }
    for (int off = 32; off; off >>= 1) {
      d0 += __shfl_xor(d0, off); d1 += __shfl_xor(d1, off);
      d2 += __shfl_xor(d2, off); d3 += __shfl_xor(d3, off);
    }
    float i0 = 1.f / (d0 + 1e-16f), i1 = 1.f / (d1 + 1e-16f);
    float i2 = 1.f / (d2 + 1e-16f), i3 = 1.f / (d3 + 1e-16f);
    for (int base = start; base < end; base += 64) {
      int cntv = min(64, end - base);
      int p = base + lane;
      float w0 = 0.f, w1 = 0.f, w2 = 0.f, w3 = 0.f;
      int srcr = 0;
      if (p < end) {
        ALPHA_P(p)
        w0 = __expf(a0 - m0) * i0; w1 = __expf(a1 - m1) * i1;
        w2 = __expf(a2 - m2) * i2; w3 = __expf(a3 - m3) * i3;
        srcr = s_;
      }
      for (int j = 0; j < cntv; ++j) {
        int sj2 = __shfl(srcr, j);
        float q0 = __shfl(w0, j), q1 = __shfl(w1, j);
        float q2 = __shfl(w2, j), q3 = __shfl(w3, j);
        const float* hr = h + (size_t)sj2 * DIM;
        float hv0 = hr[lane];
        float hv1 = has2 ? hr[64 + lane] : 0.f;
        A0 += q0 * hv0; A1 += q1 * hv0; A2 += q2 * hv0; A3 += q3 * hv0;
        B0 += q0 * hv1; B1 += q1 * hv1; B2 += q2 * hv1; B3 += q3 * hv1;
      }
    }
  }
  unsigned short* outp = agg2h + (size_t)n * KP;
  outp[lane] = f2h(A0); outp[100 + lane] = f2h(A1);
  outp[200 + lane] = f2h(A2); outp[300 + lane] = f2h(A3);
  if (has2) {
    outp[64 + lane] = f2h(B0); outp[164 + lane] = f2h(B1);
    outp[264 + lane] = f2h(B2); outp[364 + lane] = f2h(B3);
  }
  if (lane < KP - 400) outp[400 + lane] = 0;   // zero K-pad for MFMA
}

// GEMM2 via MFMA f16: C[30000,100] = agg2h[30000,416] @ B[416,112(pad)]
// No LDS. Wave = 16 rows x 7 col-tiles; A-frag 16B coalesced loads, B-frag
// pre-packed in operand order. Fused LayerNorm + ELU + residual epilogue.
__global__ __launch_bounds__(256) void k_gemm2(const _Float16* __restrict__ agg2h,
                                               const _Float16* __restrict__ Bfrag_l,
                                               const float* __restrict__ lg,
                                               const float* __restrict__ lb,
                                               float* __restrict__ h) {
  int t = threadIdx.x;
  int lane = t & 63;
  int w = t >> 6;
  int c = lane & 15;        // col within tile / A-row within tile
  int quad = lane >> 4;
  int nb = blockIdx.x * 64 + w * 16;     // wave's 16 rows

  f32x4 acc[7];
#pragma unroll
  for (int ct = 0; ct < 7; ++ct) acc[ct] = (f32x4){0.f, 0.f, 0.f, 0.f};

  const _Float16* arow = agg2h + (size_t)(nb + c) * KP + quad * 8;
#pragma unroll
  for (int ks = 0; ks < 13; ++ks) {
    half8 a = *(const half8*)(arow + ks * 32);
    const _Float16* bp = Bfrag_l + (size_t)(ks * 64 + lane) * 8;
#pragma unroll
    for (int ct = 0; ct < 7; ++ct) {
      half8 b = *(const half8*)(bp + (size_t)ct * 13 * 64 * 8);
      acc[ct] = __builtin_amdgcn_mfma_f32_16x16x32_f16(a, b, acc[ct], 0, 0, 0);
    }
  }

  // epilogue: C/D layout col=lane&15, row=quad*4+reg. LN across the 16 lanes
  // of a quad (xor 1,2,4,8 stays inside the 16-lane group).
  float gv[7], bv[7];
#pragma unroll
  for (int ct = 0; ct < 7; ++ct) {
    int col = ct * 16 + c;
    gv[ct] = (col < DIM) ? lg[col] : 0.f;
    bv[ct] = (col < DIM) ? lb[col] : 0.f;
  }
  bool c4 = c < 4;   // ct=6 valid cols: 96..99
#pragma unroll
  for (int r = 0; r < 4; ++r) {
    int n = nb + quad * 4 + r;
    float v[7];
#pragma unroll
    for (int ct = 0; ct < 7; ++ct) v[ct] = acc[ct][r];
    float s = v[0] + v[1] + v[2] + v[3] + v[4] + v[5] + (c4 ? v[6] : 0.f);
    s += __shfl_xor(s, 1); s += __shfl_xor(s, 2);
    s += __shfl_xor(s, 4); s += __shfl_xor(s, 8);
    float mu = s * 0.01f;
    float dv[7];
    float s2 = 0.f;
#pragma unroll
    for (int ct = 0; ct < 6; ++ct) { dv[ct] = v[ct] - mu; s2 += dv[ct] * dv[ct]; }
    dv[6] = c4 ? (v[6] - mu) : 0.f;
    s2 += dv[6] * dv[6];
    s2 += __shfl_xor(s2, 1); s2 += __shfl_xor(s2, 2);
    s2 += __shfl_xor(s2, 4); s2 += __shfl_xor(s2, 8);
    float rstd = rsqrtf(s2 * 0.01f + 1e-5f);
    if (n < N_NODES) {
      float* hp = h + (size_t)n * DIM;
#pragma unroll
      for (int ct = 0; ct < 7; ++ct) {
        int col = ct * 16 + c;
        if (ct < 6 || c4) {
          float y = dv[ct] * rstd * gv[ct] + bv[ct];
          y = y > 0.f ? y : (__expf(y) - 1.f);
          hp[col] += y;
        }
      }
    }
  }
}

// pool via run-length accumulation (batch is sorted): ~2 atomics/dim/block
__global__ __launch_bounds__(128) void k_pool(const float* __restrict__ h,
                                              const int* __restrict__ batch,
                                              float* __restrict__ pooled, float* __restrict__ cnt) {
  int d = threadIdx.x;
  int n0 = blockIdx.x * 64;
  int n1 = min(n0 + 64, N_NODES);
  if (n0 >= N_NODES) return;
  int curg = -1;
  float acc = 0.f, c = 0.f;
  for (int n = n0; n < n1; ++n) {
    int g = batch[n];
    if (g != curg) {
      if (curg >= 0) {
        if (d < 100) atomicAdd(&pooled[(size_t)curg * DIM + d], acc);
        if (d == 0) atomicAdd(&cnt[curg], c);
      }
      curg = g; acc = 0.f; c = 0.f;
    }
    if (d < 100) acc += h[(size_t)n * DIM + d];
    c += 1.f;
  }
  if (curg >= 0) {
    if (d < 100) atomicAdd(&pooled[(size_t)curg * DIM + d], acc);
    if (d == 0) atomicAdd(&cnt[curg], c);
  }
}

__global__ __launch_bounds__(64) void k_mlp(const float* __restrict__ pooled,
                                            const float* __restrict__ cnt,
                                            const float* __restrict__ w1, const float* __restrict__ b1,
                                            const float* __restrict__ w2, const float* __restrict__ b2,
                                            float* __restrict__ out) {
  int g = blockIdx.x;
  int j = threadIdx.x;
  float invc = 1.0f / fmaxf(cnt[g], 1.0f);
  const float* pr = pooled + (size_t)g * DIM;
  const float* wr = w1 + (size_t)j * DIM;
  float acc = 0.f;
  for (int k = 0; k < DIM; ++k) acc += pr[k] * wr[k];
  float hh = acc * invc + b1[j];
  out[NG + g * 64 + j] = hh;
  float v = hh * w2[j];
  for (int off = 32; off; off >>= 1) v += __shfl_xor(v, off);
  if (j == 0) out[g] = v + b2[0];
}

// ---------------------------------------------------------------------------
extern "C" void kernel_launch(void* const* d_in, const int* in_sizes, int n_in,
                              void* d_out, int out_size, void* d_ws, size_t ws_size,
                              hipStream_t stream) {
  (void)in_sizes; (void)n_in; (void)out_size; (void)ws_size;
  const int* x = (const int*)d_in[0];
  const int* ei = (const int*)d_in[1];
  const float* ea = (const float*)d_in[2];
  const int* batch = (const int*)d_in[3];
  const float* emb = (const float*)d_in[4];
  const float* W = (const float*)d_in[5];
  const float* We = (const float*)d_in[6];
  const float* a = (const float*)d_in[7];
  const float* ln_g = (const float*)d_in[8];
  const float* ln_b = (const float*)d_in[9];
  const float* w1 = (const float*)d_in[10];
  const float* b1 = (const float*)d_in[11];
  const float* w2 = (const float*)d_in[12];
  const float* b2 = (const float*)d_in[13];
  float* outp = (float*)d_out;

  char* ws = (char*)d_ws;
  float* h = (float*)(ws + OFF_H);
  unsigned short* agg2h = (unsigned short*)(ws + OFF_AGG2);
  int* pos = (int*)(ws + OFF_POS);
  int* deg = (int*)(ws + OFF_DEG);
  int* cursor = (int*)(ws + OFF_CURS);
  float* pooled = (float*)(ws + OFF_POOL);
  float* cnt = (float*)(ws + OFF_CNT);
  float* sc_i = (float*)(ws + OFF_SCI);
  float* sc_j = (float*)(ws + OFF_SCJ);
  unsigned short* esc = (unsigned short*)(ws + OFF_ESC);
  float* cWij = (float*)(ws + OFF_CWIJ);
  float* cWe = (float*)(ws + OFF_CWE);
  unsigned short* Bfrag = (unsigned short*)(ws + OFF_WR);
  int* indptr = (int*)(ws + OFF_INDPTR);
  int* csr_src = (int*)(ws + OFF_CSRS);
  int* bsum = (int*)(ws + OFF_BSUM);

  k_init<<<11719, 256, 0, stream>>>(x, emb, h, deg, cursor);
  k_fold<<<29, 256, 0, stream>>>(W, We, a, cWij, cWe);
  k_bfrag<<<1092, 256, 0, stream>>>(W, Bfrag);
  k_deg<<<1993, 256, 0, stream>>>(ei, deg);
  k_scan1<<<30, 1024, 0, stream>>>(deg, indptr, bsum);
  k_scan2<<<1, 64, 0, stream>>>(bsum);
  k_scan3<<<30, 1024, 0, stream>>>(indptr, bsum);
  k_scatter<<<1993, 256, 0, stream>>>(ei, indptr, cursor, csr_src, pos, esc);
  k_escore<<<7500, 384, 0, stream>>>(ea, cWe, pos, esc);

  for (int l = 0; l < NL; ++l) {
    k_score<<<118, 256, 0, stream>>>(h, cWij + l * 800, sc_i, sc_j);
    k_aggr<<<7500, 256, 0, stream>>>(h, sc_i, sc_j, esc + (size_t)l * EP_EDGES * 4,
                                     indptr, csr_src, agg2h);
    k_gemm2<<<469, 256, 0, stream>>>((const _Float16*)agg2h,
                                     (const _Float16*)(Bfrag + (size_t)l * 7 * 13 * 64 * 8),
                                     ln_g + l * 100, ln_b + l * 100, h);
  }

  hipMemsetAsync(ws + OFF_POOL, 0, 51200 + 512, stream);
  k_pool<<<469, 128, 0, stream>>>(h, batch, pooled, cnt);
  k_mlp<<<128, 64, 0, stream>>>(pooled, cnt, w1, b1, w2, b2, outp);
}